// Round 1
// baseline (19298.013 us; speedup 1.0000x reference)
//
#include <hip/hip_runtime.h>
#include <math.h>

// Problem dims
#define BB   64      // batch
#define TT   160     // seq len
#define EE   512     // embed dim
#define HH   1024    // hidden dim
#define G4   4096    // 4*H
#define ROWS 128     // 2*B (both LSTMs batched together)
#define KTOT 1536    // E + H (fused input+recurrent GEMM reduction)
#define KHALF 768    // K split in 2 for occupancy

// GEMM tile
#define MT 64
#define NT 64
#define KT 16

// gates[r,n] = sum_k A[r,k]*W[n,k] (+ bias[n] in part 0)
// A[r,k] = (k<E) ? emb[tok(r,t)][k] : h[r][k-E]
// W[n,k] = (k<E) ? Wih[n][k]        : Whh[n][k-E]
__global__ __launch_bounds__(256) void step_gemm(
    const int* __restrict__ ctx, const int* __restrict__ rsp,
    const float* __restrict__ emb, const float* __restrict__ Wih,
    const float* __restrict__ Whh, const float* __restrict__ bih,
    const float* __restrict__ bhh, const float* __restrict__ h,
    float* __restrict__ gates, int t)
{
    __shared__ float As[MT][KT + 1];
    __shared__ float Ws[NT][KT + 1];
    __shared__ int   toks[MT];

    const int r0    = blockIdx.y * MT;
    const int n0    = blockIdx.x * NT;
    const int part  = blockIdx.z;          // K-split: 0 or 1
    const int kbase = part * KHALF;
    const int tid   = threadIdx.x;

    if (tid < MT) {
        int r = r0 + tid;
        toks[tid] = (r < BB) ? ctx[r * TT + t] : rsp[(r - BB) * TT + t];
    }
    __syncthreads();

    const int tc = tid & 15;   // 16 col groups x 4 cols
    const int tr = tid >> 4;   // 16 row groups x 4 rows
    float acc[4][4] = {};

    for (int kt = 0; kt < KHALF; kt += KT) {
        const int k0 = kbase + kt;
        // stage A tile: 64x16 = 1024 elems, 4/thread
        #pragma unroll
        for (int i = tid; i < MT * KT; i += 256) {
            int r = i >> 4, k = i & 15;
            int kg = k0 + k;
            As[r][k] = (kg < EE) ? emb[(size_t)toks[r] * EE + kg]
                                 : h[(size_t)(r0 + r) * HH + (kg - EE)];
        }
        // stage W tile: 64x16 = 1024 elems, 4/thread
        #pragma unroll
        for (int i = tid; i < NT * KT; i += 256) {
            int n = i >> 4, k = i & 15;
            int kg = k0 + k;
            int ng = n0 + n;
            Ws[n][k] = (kg < EE) ? Wih[(size_t)ng * EE + kg]
                                 : Whh[(size_t)ng * HH + (kg - EE)];
        }
        __syncthreads();
        #pragma unroll
        for (int k = 0; k < KT; ++k) {
            float a[4], w[4];
            #pragma unroll
            for (int q = 0; q < 4; ++q) a[q] = As[tr * 4 + q][k];
            #pragma unroll
            for (int q = 0; q < 4; ++q) w[q] = Ws[tc * 4 + q][k];
            #pragma unroll
            for (int i2 = 0; i2 < 4; ++i2)
                #pragma unroll
                for (int j2 = 0; j2 < 4; ++j2)
                    acc[i2][j2] += a[i2] * w[j2];
        }
        __syncthreads();
    }

    float* gp = gates + (size_t)part * ROWS * G4;
    #pragma unroll
    for (int i2 = 0; i2 < 4; ++i2) {
        int r = r0 + tr * 4 + i2;
        #pragma unroll
        for (int j2 = 0; j2 < 4; ++j2) {
            int n = n0 + tc * 4 + j2;
            float v = acc[i2][j2];
            if (part == 0) v += bih[n] + bhh[n];
            gp[(size_t)r * G4 + n] = v;
        }
    }
}

// LSTM cell pointwise update: i,f,g,o gate order (PyTorch)
__global__ __launch_bounds__(256) void lstm_update(
    const float* __restrict__ gates, float* __restrict__ h, float* __restrict__ c)
{
    int idx = blockIdx.x * 256 + threadIdx.x;   // ROWS*HH threads
    int r = idx >> 10;          // /HH
    int j = idx & (HH - 1);
    const float* g0 = gates + (size_t)r * G4;
    const float* g1 = gates + (size_t)(ROWS + r) * G4;
    float gi = g0[j]          + g1[j];
    float gf = g0[HH + j]     + g1[HH + j];
    float gg = g0[2 * HH + j] + g1[2 * HH + j];
    float go = g0[3 * HH + j] + g1[3 * HH + j];
    float si = 1.0f / (1.0f + expf(-gi));
    float sf = 1.0f / (1.0f + expf(-gf));
    float so = 1.0f / (1.0f + expf(-go));
    float tg = tanhf(gg);
    float cn = sf * c[idx] + si * tg;
    c[idx] = cn;
    h[idx] = so * tanhf(cn);
}

// out[b] = sigmoid( sum_ij ch[b,i] * M[i,j] * rh[b,j] )
__global__ __launch_bounds__(256) void bilinear(
    const float* __restrict__ h, const float* __restrict__ M, float* __restrict__ out)
{
    int b = blockIdx.x;
    __shared__ float chs[HH];
    __shared__ float red[256];
    const float* ch = h + (size_t)b * HH;
    const float* rh = h + (size_t)(BB + b) * HH;
    for (int i = threadIdx.x; i < HH; i += 256) chs[i] = ch[i];
    __syncthreads();
    float vj[4] = {0.f, 0.f, 0.f, 0.f};
    for (int i = 0; i < HH; ++i) {
        float chi = chs[i];
        const float* Mr = M + (size_t)i * HH;
        #pragma unroll
        for (int q = 0; q < 4; ++q)
            vj[q] += chi * Mr[threadIdx.x + q * 256];   // coalesced over lanes
    }
    float acc = 0.f;
    #pragma unroll
    for (int q = 0; q < 4; ++q) acc += vj[q] * rh[threadIdx.x + q * 256];
    red[threadIdx.x] = acc;
    __syncthreads();
    for (int s = 128; s > 0; s >>= 1) {
        if (threadIdx.x < s) red[threadIdx.x] += red[threadIdx.x + s];
        __syncthreads();
    }
    if (threadIdx.x == 0) out[b] = 1.0f / (1.0f + expf(-red[0]));
}

extern "C" void kernel_launch(void* const* d_in, const int* in_sizes, int n_in,
                              void* d_out, int out_size, void* d_ws, size_t ws_size,
                              hipStream_t stream) {
    const int*   ctx = (const int*)d_in[0];
    const int*   rsp = (const int*)d_in[1];
    const float* emb = (const float*)d_in[2];
    const float* Wih = (const float*)d_in[3];
    const float* Whh = (const float*)d_in[4];
    const float* bih = (const float*)d_in[5];
    const float* bhh = (const float*)d_in[6];
    const float* M   = (const float*)d_in[7];
    float* out = (float*)d_out;

    // workspace layout (f32): h[128*1024] | c[128*1024] | gates[2][128*4096]
    float* h     = (float*)d_ws;
    float* c     = h + ROWS * HH;
    float* gates = c + ROWS * HH;
    hipMemsetAsync(h, 0, (size_t)2 * ROWS * HH * sizeof(float), stream);

    dim3 grid(G4 / NT, ROWS / MT, 2);  // 64 x 2 x 2 = 256 blocks
    for (int t = 0; t < TT; ++t) {
        step_gemm<<<grid, 256, 0, stream>>>(ctx, rsp, emb, Wih, Whh, bih, bhh, h, gates, t);
        lstm_update<<<ROWS * HH / 256, 256, 0, stream>>>(gates, h, c);
    }
    bilinear<<<BB, 256, 0, stream>>>(h, M, out);
}

// Round 2
// 2343.986 us; speedup vs baseline: 8.2330x; 8.2330x over previous
//
#include <hip/hip_runtime.h>
#include <math.h>

// DualEncoder: two LSTMs (B=64,T=160,E=512,H=1024) + bilinear sigmoid.
// Strategy: bf16 MFMA GEMMs (f32 accum), f32 cell state.
//   mode 2 (ws>=208MB): precompute X = emb[tok]@Wih^T + bias for all t (parallel),
//                       per-step GEMM is only h@Whh^T (K=1024).
//   mode 1 (ws>=48MB) : per-step fused [emb|h]@[Wih|Whh]^T (K=1536), weights pre-converted to bf16.
//   mode 0 (ws>=4.8MB): same but converts f32 sources during LDS staging.

#define BB 64
#define TT 160
#define EE 512
#define HH 1024
#define G4 4096
#define ROWS 128

typedef unsigned short u16;
typedef __attribute__((ext_vector_type(8))) __bf16 bf16x8;
typedef __attribute__((ext_vector_type(8))) short short8;
typedef __attribute__((ext_vector_type(4))) short short4v;
typedef __attribute__((ext_vector_type(4))) float f32x4;

__device__ inline u16 f2b(float f) {                 // f32 -> bf16 RNE
    unsigned u = __float_as_uint(f);
    u = u + 0x7fffu + ((u >> 16) & 1u);
    return (u16)(u >> 16);
}
__device__ inline float b2f(u16 s) { return __uint_as_float(((unsigned)s) << 16); }

__device__ inline f32x4 mfma16(const u16* a, const u16* b, f32x4 c) {
    bf16x8 av = __builtin_bit_cast(bf16x8, *(const short8*)a);
    bf16x8 bv = __builtin_bit_cast(bf16x8, *(const short8*)b);
    return __builtin_amdgcn_mfma_f32_16x16x32_bf16(av, bv, c, 0, 0, 0);
}

// generic f32 -> bf16 conversion, 4 elems/thread
__global__ __launch_bounds__(256) void cvt_kernel(const float* __restrict__ in,
                                                  u16* __restrict__ out, int n4) {
    int i = blockIdx.x * 256 + threadIdx.x;
    if (i < n4) {
        f32x4 v = *(const f32x4*)(in + (size_t)i * 4);
        short4v o;
        o.x = (short)f2b(v.x); o.y = (short)f2b(v.y);
        o.z = (short)f2b(v.z); o.w = (short)f2b(v.w);
        *(short4v*)(out + (size_t)i * 4) = o;
    }
}

// Precompute Xg[t][r][n] = bias[n] + emb[tok(r,t)] @ Wih^T  (bf16 out)
// 128x128 tile, K=512, 4 waves each 64x64 (4x4 frags of 16x16x32).
__global__ __launch_bounds__(256) void pre_gemm(
    const int* __restrict__ ctx, const int* __restrict__ rsp,
    const u16* __restrict__ embb, const u16* __restrict__ Wihb,
    const float* __restrict__ bih, const float* __restrict__ bhh,
    u16* __restrict__ xg)
{
    __shared__ __align__(16) u16 As[128][32];
    __shared__ __align__(16) u16 Ws[128][32];
    __shared__ int toks[128];
    const int tid = threadIdx.x;
    const int n0 = blockIdx.x * 128;
    const int t  = blockIdx.y;

    if (tid < 128) {
        int r = tid;
        toks[tid] = (r < BB) ? ctx[r * TT + t] : rsp[(r - BB) * TT + t];
    }
    __syncthreads();

    const int lane = tid & 63, wave = tid >> 6;
    const int wr = (wave >> 1) * 64, wc = (wave & 1) * 64;
    const int l15 = lane & 15, l4 = lane >> 4;

    f32x4 acc[4][4] = {};

    for (int it = 0; it < 16; ++it) {
        const int kg = it * 32;
        #pragma unroll
        for (int half = 0; half < 2; ++half) {
            int cc = tid + half * 256;           // 0..511 chunks of 8 bf16
            int row = cc >> 2, seg = (cc & 3) * 8;
            *(short8*)&As[row][seg] = *(const short8*)(embb + (size_t)toks[row] * EE + kg + seg);
            *(short8*)&Ws[row][seg] = *(const short8*)(Wihb + (size_t)(n0 + row) * EE + kg + seg);
        }
        __syncthreads();
        #pragma unroll
        for (int mf = 0; mf < 4; ++mf)
            #pragma unroll
            for (int nf = 0; nf < 4; ++nf)
                acc[mf][nf] = mfma16(&As[wr + mf * 16 + l15][l4 * 8],
                                     &Ws[wc + nf * 16 + l15][l4 * 8], acc[mf][nf]);
        __syncthreads();
    }

    u16* xp = xg + (size_t)t * ROWS * G4;
    #pragma unroll
    for (int mf = 0; mf < 4; ++mf)
        #pragma unroll
        for (int nf = 0; nf < 4; ++nf) {
            int n = n0 + wc + nf * 16 + l15;
            float bias = bih[n] + bhh[n];
            #pragma unroll
            for (int q = 0; q < 4; ++q) {
                int r = wr + mf * 16 + l4 * 4 + q;
                xp[(size_t)r * G4 + n] = f2b(acc[mf][nf][q] + bias);
            }
        }
}

// Per-step GEMM: gates_part[r][n] = sum_k A[r,k] W[n,k]
//  XPRE:  K = 1024 (h @ Whh^T), split in 2 parts of 512
//  FUSED: K = 1536 ([emb|h] @ [Wih|Whh]^T), split in 2 parts of 768
// 64x64 tile, 4 waves each 32x32 (2x2 frags).
template<bool CONV, bool XPRE>
__global__ __launch_bounds__(256) void step_gemm(
    const int* __restrict__ ctx, const int* __restrict__ rsp,
    const float* __restrict__ emb, const float* __restrict__ Wih, const float* __restrict__ Whh,
    const u16* __restrict__ embb, const u16* __restrict__ Wihb, const u16* __restrict__ Whhb,
    const u16* __restrict__ hb, float* __restrict__ gates, int t)
{
    __shared__ __align__(16) u16 As[64][32];
    __shared__ __align__(16) u16 Ws[64][32];
    __shared__ int toks[64];

    const int tid = threadIdx.x;
    const int n0 = blockIdx.x * 64;
    const int r0 = blockIdx.y * 64;
    const int part = blockIdx.z;

    if (!XPRE) {
        if (tid < 64) {
            int r = r0 + tid;
            toks[tid] = (r < BB) ? ctx[r * TT + t] : rsp[(r - BB) * TT + t];
        }
        __syncthreads();
    }

    const int lane = tid & 63, wave = tid >> 6;
    const int wr = (wave >> 1) * 32, wc = (wave & 1) * 32;
    const int l15 = lane & 15, l4 = lane >> 4;

    f32x4 acc[2][2] = {};

    const int kstart = XPRE ? (EE + part * 512) : part * 768;
    const int niter  = XPRE ? 16 : 24;

    const int srow = tid >> 2;         // 0..63 (row staged by this thread)
    const int sseg = (tid & 3) * 8;    // k-offset (8 bf16 = 16B chunk)

    for (int it = 0; it < niter; ++it) {
        const int kg = kstart + it * 32;
        const int kk = kg + sseg;
        // ---- stage A tile (64 rows x 32 k)
        if (!XPRE && kg < EE) {
            int tok = toks[srow];
            if (CONV) {
                const float* s = emb + (size_t)tok * EE + kk;
                #pragma unroll
                for (int q = 0; q < 8; ++q) As[srow][sseg + q] = f2b(s[q]);
            } else {
                *(short8*)&As[srow][sseg] = *(const short8*)(embb + (size_t)tok * EE + kk);
            }
        } else {
            *(short8*)&As[srow][sseg] = *(const short8*)(hb + (size_t)(r0 + srow) * HH + (kk - EE));
        }
        // ---- stage B tile (64 rows x 32 k)
        {
            int ng = n0 + srow;
            if (!XPRE && kg < EE) {
                if (CONV) {
                    const float* s = Wih + (size_t)ng * EE + kk;
                    #pragma unroll
                    for (int q = 0; q < 8; ++q) Ws[srow][sseg + q] = f2b(s[q]);
                } else {
                    *(short8*)&Ws[srow][sseg] = *(const short8*)(Wihb + (size_t)ng * EE + kk);
                }
            } else {
                if (CONV) {
                    const float* s = Whh + (size_t)ng * HH + (kk - EE);
                    #pragma unroll
                    for (int q = 0; q < 8; ++q) Ws[srow][sseg + q] = f2b(s[q]);
                } else {
                    *(short8*)&Ws[srow][sseg] = *(const short8*)(Whhb + (size_t)ng * HH + (kk - EE));
                }
            }
        }
        __syncthreads();
        #pragma unroll
        for (int mf = 0; mf < 2; ++mf)
            #pragma unroll
            for (int nf = 0; nf < 2; ++nf)
                acc[mf][nf] = mfma16(&As[wr + mf * 16 + l15][l4 * 8],
                                     &Ws[wc + nf * 16 + l15][l4 * 8], acc[mf][nf]);
        __syncthreads();
    }

    float* gp = gates + (size_t)part * ROWS * G4;
    #pragma unroll
    for (int mf = 0; mf < 2; ++mf)
        #pragma unroll
        for (int nf = 0; nf < 2; ++nf)
            #pragma unroll
            for (int q = 0; q < 4; ++q) {
                int r = r0 + wr + mf * 16 + l4 * 4 + q;
                int n = n0 + wc + nf * 16 + l15;
                gp[(size_t)r * G4 + n] = acc[mf][nf][q];
            }
}

// Cell update: gates = part0 + part1 (+ Xg or + bias); c,h update. h stored bf16.
template<bool XPRE>
__global__ __launch_bounds__(256) void lstm_update(
    const float* __restrict__ gates, const u16* __restrict__ xg,
    const float* __restrict__ bih, const float* __restrict__ bhh,
    u16* __restrict__ hb, float* __restrict__ c, int t)
{
    int idx = blockIdx.x * 256 + threadIdx.x;    // 32768 threads, 4 elems each
    int r = idx >> 8;
    int jj = (idx & 255) * 4;
    const float* g0 = gates + (size_t)r * G4;
    const float* g1 = gates + (size_t)(ROWS + r) * G4;
    float gate[4][4];
    #pragma unroll
    for (int g = 0; g < 4; ++g) {
        int n = g * HH + jj;
        f32x4 a = *(const f32x4*)(g0 + n);
        f32x4 b = *(const f32x4*)(g1 + n);
        #pragma unroll
        for (int q = 0; q < 4; ++q) gate[g][q] = a[q] + b[q];
        if (XPRE) {
            const u16* xp = xg + ((size_t)t * ROWS + r) * G4 + n;
            #pragma unroll
            for (int q = 0; q < 4; ++q) gate[g][q] += b2f(xp[q]);
        } else {
            #pragma unroll
            for (int q = 0; q < 4; ++q) gate[g][q] += bih[n + q] + bhh[n + q];
        }
    }
    int cidx = r * HH + jj;
    f32x4 cv = *(const f32x4*)(c + cidx);
    f32x4 cn;
    short4v hn;
    #pragma unroll
    for (int q = 0; q < 4; ++q) {
        float si = 1.f / (1.f + expf(-gate[0][q]));
        float sf = 1.f / (1.f + expf(-gate[1][q]));
        float tg = tanhf(gate[2][q]);
        float so = 1.f / (1.f + expf(-gate[3][q]));
        float cval = sf * cv[q] + si * tg;
        cn[q] = cval;
        float hval = so * tanhf(cval);
        ((short*)&hn)[q] = (short)f2b(hval);
    }
    *(f32x4*)(c + cidx) = cn;
    *(short4v*)(hb + cidx) = hn;
}

// out[b] = sigmoid( ch . M . rh )
__global__ __launch_bounds__(256) void bilinear(
    const u16* __restrict__ hb, const float* __restrict__ M, float* __restrict__ out)
{
    int b = blockIdx.x;
    __shared__ float chs[HH];
    __shared__ float red[256];
    const u16* ch = hb + (size_t)b * HH;
    const u16* rh = hb + (size_t)(BB + b) * HH;
    for (int i = threadIdx.x; i < HH; i += 256) chs[i] = b2f(ch[i]);
    __syncthreads();
    float vj[4] = {0.f, 0.f, 0.f, 0.f};
    for (int i = 0; i < HH; ++i) {
        float chi = chs[i];
        const float* Mr = M + (size_t)i * HH;
        #pragma unroll
        for (int q = 0; q < 4; ++q) vj[q] += chi * Mr[threadIdx.x + q * 256];
    }
    float acc = 0.f;
    #pragma unroll
    for (int q = 0; q < 4; ++q) acc += vj[q] * b2f(rh[threadIdx.x + q * 256]);
    red[threadIdx.x] = acc;
    __syncthreads();
    for (int s = 128; s > 0; s >>= 1) {
        if (threadIdx.x < s) red[threadIdx.x] += red[threadIdx.x + s];
        __syncthreads();
    }
    if (threadIdx.x == 0) out[b] = 1.0f / (1.0f + expf(-red[0]));
}

extern "C" void kernel_launch(void* const* d_in, const int* in_sizes, int n_in,
                              void* d_out, int out_size, void* d_ws, size_t ws_size,
                              hipStream_t stream) {
    const int*   ctx = (const int*)d_in[0];
    const int*   rsp = (const int*)d_in[1];
    const float* emb = (const float*)d_in[2];
    const float* Wih = (const float*)d_in[3];
    const float* Whh = (const float*)d_in[4];
    const float* bih = (const float*)d_in[5];
    const float* bhh = (const float*)d_in[6];
    const float* M   = (const float*)d_in[7];
    float* out = (float*)d_out;

    // workspace layout
    char* w = (char*)d_ws;
    u16*   hb    = (u16*)w;   w += (size_t)ROWS * HH * 2;          // 256 KB
    float* c     = (float*)w; w += (size_t)ROWS * HH * 4;          // 512 KB
    float* gates = (float*)w; w += (size_t)2 * ROWS * G4 * 4;      // 4 MB
    size_t base_need = (size_t)(w - (char*)d_ws);
    u16*   embb  = (u16*)w;   w += (size_t)32000 * EE * 2;         // 32.77 MB
    u16*   Wihb  = (u16*)w;   w += (size_t)G4 * EE * 2;            // 4 MB
    u16*   Whhb  = (u16*)w;   w += (size_t)G4 * HH * 2;            // 8 MB
    size_t conv_need = (size_t)(w - (char*)d_ws);
    u16*   xg    = (u16*)w;   w += (size_t)TT * ROWS * G4 * 2;     // 160 MB
    size_t xpre_need = (size_t)(w - (char*)d_ws);

    int mode = (ws_size >= xpre_need) ? 2 : (ws_size >= conv_need) ? 1 : 0;
    (void)base_need;

    hipMemsetAsync(hb, 0, (size_t)ROWS * HH * 2, stream);
    hipMemsetAsync(c,  0, (size_t)ROWS * HH * 4, stream);

    if (mode >= 1) {
        cvt_kernel<<<16000, 256, 0, stream>>>(emb, embb, 32000 * EE / 4);
        cvt_kernel<<<2048,  256, 0, stream>>>(Wih, Wihb, G4 * EE / 4);
        cvt_kernel<<<4096,  256, 0, stream>>>(Whh, Whhb, G4 * HH / 4);
    }
    if (mode == 2) {
        pre_gemm<<<dim3(G4 / 128, TT), 256, 0, stream>>>(ctx, rsp, embb, Wihb, bih, bhh, xg);
    }

    dim3 sg(G4 / 64, ROWS / 64, 2);   // 64 x 2 x 2 = 256 blocks
    for (int t = 0; t < TT; ++t) {
        if (mode == 2)
            step_gemm<false, true><<<sg, 256, 0, stream>>>(ctx, rsp, emb, Wih, Whh,
                embb, Wihb, Whhb, hb, gates, t);
        else if (mode == 1)
            step_gemm<false, false><<<sg, 256, 0, stream>>>(ctx, rsp, emb, Wih, Whh,
                embb, Wihb, Whhb, hb, gates, t);
        else
            step_gemm<true, false><<<sg, 256, 0, stream>>>(ctx, rsp, emb, Wih, Whh,
                embb, Wihb, Whhb, hb, gates, t);
        if (mode == 2)
            lstm_update<true><<<128, 256, 0, stream>>>(gates, xg, bih, bhh, hb, c, t);
        else
            lstm_update<false><<<128, 256, 0, stream>>>(gates, xg, bih, bhh, hb, c, t);
    }
    bilinear<<<BB, 256, 0, stream>>>(hb, M, out);
}

// Round 3
// 2164.074 us; speedup vs baseline: 8.9174x; 1.0831x over previous
//
#include <hip/hip_runtime.h>
#include <math.h>

// DualEncoder: two LSTMs (B=64,T=160,E=512,H=1024) + bilinear sigmoid.
// mode 2: precompute X = emb[tok]@Wih^T + bias (parallel GEMM), fused per-step
//         kernel does h@Whh^T (K=1024) + cell update in one launch.
// mode 1: no X; fused per-step kernel with K=1536 ([emb|h]@[Wih|Whh]^T).
// mode 0: fallback = round-1 proven kernels (f32 sources, converts in staging).

#define BB 64
#define TT 160
#define EE 512
#define HH 1024
#define G4 4096
#define ROWS 128

typedef unsigned short u16;
typedef unsigned int u32;
typedef __attribute__((ext_vector_type(8))) __bf16 bf16x8;
typedef __attribute__((ext_vector_type(8))) short short8;
typedef __attribute__((ext_vector_type(4))) short short4v;
typedef __attribute__((ext_vector_type(4))) float f32x4;

__device__ __forceinline__ u16 f2b(float f) {          // f32 -> bf16 RNE
    unsigned u = __float_as_uint(f);
    u = u + 0x7fffu + ((u >> 16) & 1u);
    return (u16)(u >> 16);
}
__device__ __forceinline__ float b2f(u16 s) { return __uint_as_float(((unsigned)s) << 16); }

__device__ __forceinline__ f32x4 mfma16(short8 a, short8 b, f32x4 c) {
    return __builtin_amdgcn_mfma_f32_16x16x32_bf16(
        __builtin_bit_cast(bf16x8, a), __builtin_bit_cast(bf16x8, b), c, 0, 0, 0);
}

// async global->LDS 16B: lds dest = wave-uniform base + lane*16 (linear);
// per-lane global src carries the inverse swizzle.
__device__ __forceinline__ void g2l16(const void* gsrc, void* ldst) {
    __builtin_amdgcn_global_load_lds(
        (const __attribute__((address_space(1))) u32*)gsrc,
        (__attribute__((address_space(3))) u32*)ldst, 16, 0, 0);
}

// ---------------- f32 -> bf16 bulk convert ----------------
__global__ __launch_bounds__(256) void cvt_kernel(const float* __restrict__ in,
                                                  u16* __restrict__ out, int n4) {
    int i = blockIdx.x * 256 + threadIdx.x;
    if (i < n4) {
        f32x4 v = *(const f32x4*)(in + (size_t)i * 4);
        short4v o;
        o.x = (short)f2b(v.x); o.y = (short)f2b(v.y);
        o.z = (short)f2b(v.z); o.w = (short)f2b(v.w);
        *(short4v*)(out + (size_t)i * 4) = o;
    }
}

// ---------------- X precompute: X[t][r][n] = bias[n] + emb[tok(r,t)]@Wih^T ----
// grid (32, 160), 256 thr; block tile 128 rows x 128 cols, K=512, BK=64 dbuf.
__global__ __launch_bounds__(256) void pre_gemm2(
    const int* __restrict__ ctx, const int* __restrict__ rsp,
    const u16* __restrict__ embb, const u16* __restrict__ Wihb,
    const float* __restrict__ bih, const float* __restrict__ bhh,
    u16* __restrict__ xg)
{
    __shared__ __align__(16) u16 As[2][128][64];
    __shared__ __align__(16) u16 Ws[2][128][64];
    __shared__ int toks[128];
    const int tid = threadIdx.x;
    const int n0 = blockIdx.x * 128;
    const int t  = blockIdx.y;

    if (tid < 128) {
        int r = tid;
        toks[tid] = (r < BB) ? ctx[r * TT + t] : rsp[(r - BB) * TT + t];
    }
    __syncthreads();

    // staging: 1024 16B-chunks per tile, 4 per thread; dest linear, src swizzled
    const u16* asrc[4]; const u16* bsrc[4];
    #pragma unroll
    for (int q = 0; q < 4; ++q) {
        int i = tid + q * 256;
        int row = i >> 3, c16 = i & 7;
        int scol = ((c16 ^ (row & 7)) * 8);
        asrc[q] = embb + (size_t)toks[row] * EE + scol;
        bsrc[q] = Wihb + (size_t)(n0 + row) * EE + scol;
    }

    const int lane = tid & 63, wave = tid >> 6;
    const int wr = (wave >> 1) * 64, wc = (wave & 1) * 64;
    const int l15 = lane & 15, l4 = lane >> 4;
    f32x4 acc[4][4] = {};

    // prologue stage chunk 0
    #pragma unroll
    for (int q = 0; q < 4; ++q) {
        g2l16(asrc[q], (char*)&As[0][0][0] + (tid + q * 256) * 16);
        g2l16(bsrc[q], (char*)&Ws[0][0][0] + (tid + q * 256) * 16);
    }
    for (int it = 0; it < 8; ++it) {
        __syncthreads();
        if (it + 1 < 8) {
            int kk = (it + 1) * 64, bs = (it + 1) & 1;
            #pragma unroll
            for (int q = 0; q < 4; ++q) {
                g2l16(asrc[q] + kk, (char*)&As[bs][0][0] + (tid + q * 256) * 16);
                g2l16(bsrc[q] + kk, (char*)&Ws[bs][0][0] + (tid + q * 256) * 16);
            }
        }
        const int b = it & 1;
        #pragma unroll
        for (int ks = 0; ks < 2; ++ks) {
            int c16 = ks * 4 + l4;
            short8 a[4], w[4];
            #pragma unroll
            for (int mf = 0; mf < 4; ++mf) {
                int R = wr + mf * 16 + l15;
                a[mf] = *(const short8*)((const char*)&As[b][0][0] + R * 128 + ((c16 ^ (R & 7)) << 4));
            }
            #pragma unroll
            for (int nf = 0; nf < 4; ++nf) {
                int Nn = wc + nf * 16 + l15;
                w[nf] = *(const short8*)((const char*)&Ws[b][0][0] + Nn * 128 + ((c16 ^ (Nn & 7)) << 4));
            }
            #pragma unroll
            for (int mf = 0; mf < 4; ++mf)
                #pragma unroll
                for (int nf = 0; nf < 4; ++nf)
                    acc[mf][nf] = mfma16(a[mf], w[nf], acc[mf][nf]);
        }
    }

    u16* xp = xg + (size_t)t * ROWS * G4;
    #pragma unroll
    for (int nf = 0; nf < 4; ++nf) {
        int n = n0 + wc + nf * 16 + l15;
        float bias = bih[n] + bhh[n];
        #pragma unroll
        for (int mf = 0; mf < 4; ++mf)
            #pragma unroll
            for (int q = 0; q < 4; ++q) {
                int r = wr + mf * 16 + l4 * 4 + q;
                xp[(size_t)r * G4 + n] = f2b(acc[mf][nf][q] + bias);
            }
    }
}

// ---------------- fused per-step kernel ----------------
// grid 256: cg = bx&127 (8 h-cols), rg = bx>>7 (64 rows). GEMM 64x32 (+K) then
// cell update in-kernel. MODE 2: K=1024 over h (X precomputed); MODE 1: K=1536.
template<int MODE>
__global__ __launch_bounds__(256) void step_fused(
    const int* __restrict__ ctx, const int* __restrict__ rsp,
    const u16* __restrict__ embb, const u16* __restrict__ Wihb,
    const u16* __restrict__ Whhb, const u16* __restrict__ xg,
    const float* __restrict__ bih, const float* __restrict__ bhh,
    const u16* __restrict__ hin, u16* __restrict__ hout,
    float* __restrict__ c_ws, int t)
{
    __shared__ __align__(16) u16 As[2][64][64];   // 2*8KB
    __shared__ __align__(16) u16 Ws[2][32][64];   // 2*4KB
    __shared__ float gs[64][32];                  // 8KB
    __shared__ int toks[64];

    const int tid = threadIdx.x;
    const int cg = blockIdx.x & 127, rg = blockIdx.x >> 7;
    const int r0 = rg * 64, j0 = cg * 8;

    if (MODE == 1) {
        if (tid < 64) {
            int r = r0 + tid;
            toks[tid] = (r < BB) ? ctx[r * TT + t] : rsp[(r - BB) * TT + t];
        }
        __syncthreads();
    }

    // A staging: 512 chunks (rows 0..63), 2 per thread
    const int arow0 = tid >> 3, c16a = tid & 7;
    const int arow1 = arow0 + 32;
    const int acol0 = ((c16a ^ (arow0 & 7)) * 8);
    const int acol1 = ((c16a ^ (arow1 & 7)) * 8);
    const u16* hA0 = hin + (size_t)(r0 + arow0) * HH + acol0;
    const u16* hA1 = hin + (size_t)(r0 + arow1) * HH + acol1;
    const u16* eA0 = nullptr; const u16* eA1 = nullptr;
    if (MODE == 1) {
        eA0 = embb + (size_t)toks[arow0] * EE + acol0;
        eA1 = embb + (size_t)toks[arow1] * EE + acol1;
    }
    // B staging: 256 chunks (gate-col rows 0..31), 1 per thread
    const int nn = tid >> 3, c16b = tid & 7;
    const int bcol = ((c16b ^ (nn & 7)) * 8);
    const int wrow = (nn >> 3) * HH + j0 + (nn & 7);   // Whh/Wih row index
    const u16* wHh = Whhb + (size_t)wrow * HH + bcol;
    const u16* wIh = (MODE == 1) ? (Wihb + (size_t)wrow * EE + bcol) : nullptr;

    const int NK = (MODE == 1) ? 24 : 16;

    auto stage = [&](int bs, int it) {
        int kk = it * 64;
        const u16 *s0, *s1, *sw;
        if (MODE == 1 && kk < EE) {
            s0 = eA0 + kk; s1 = eA1 + kk; sw = wIh + kk;
        } else {
            int kh = (MODE == 1) ? kk - EE : kk;
            s0 = hA0 + kh; s1 = hA1 + kh; sw = wHh + kh;
        }
        g2l16(s0, (char*)&As[bs][0][0] + tid * 16);
        g2l16(s1, (char*)&As[bs][0][0] + (tid + 256) * 16);
        g2l16(sw, (char*)&Ws[bs][0][0] + tid * 16);
    };

    const int lane = tid & 63, wave = tid >> 6;
    const int wr = wave * 16;
    const int l15 = lane & 15, l4 = lane >> 4;
    f32x4 acc[2] = {};

    stage(0, 0);
    for (int it = 0; it < NK; ++it) {
        __syncthreads();
        if (it + 1 < NK) stage((it + 1) & 1, it + 1);
        const int b = it & 1;
        #pragma unroll
        for (int ks = 0; ks < 2; ++ks) {
            int c16 = ks * 4 + l4;
            int R = wr + l15;
            short8 a = *(const short8*)((const char*)&As[b][0][0] + R * 128 + ((c16 ^ (R & 7)) << 4));
            #pragma unroll
            for (int nf = 0; nf < 2; ++nf) {
                int Nn = nf * 16 + l15;
                short8 w = *(const short8*)((const char*)&Ws[b][0][0] + Nn * 128 + ((c16 ^ (Nn & 7)) << 4));
                acc[nf] = mfma16(a, w, acc[nf]);
            }
        }
    }
    __syncthreads();
    #pragma unroll
    for (int nf = 0; nf < 2; ++nf)
        #pragma unroll
        for (int q = 0; q < 4; ++q)
            gs[wr + l4 * 4 + q][nf * 16 + l15] = acc[nf][q];
    __syncthreads();

    // cell update: 2 adjacent cells per thread
    const int e = tid * 2;
    const int row = e >> 3, jj = e & 7;      // jj in {0,2,4,6}
    const int rglob = r0 + row;
    float g0[4], g1[4];
    #pragma unroll
    for (int g = 0; g < 4; ++g) { g0[g] = gs[row][g * 8 + jj]; g1[g] = gs[row][g * 8 + jj + 1]; }
    if (MODE == 2) {
        const u16* xp = xg + ((size_t)t * ROWS + rglob) * G4 + j0 + jj;
        #pragma unroll
        for (int g = 0; g < 4; ++g) { g0[g] += b2f(xp[g * HH]); g1[g] += b2f(xp[g * HH + 1]); }
    } else {
        #pragma unroll
        for (int g = 0; g < 4; ++g) {
            int n = g * HH + j0 + jj;
            g0[g] += bih[n] + bhh[n];
            g1[g] += bih[n + 1] + bhh[n + 1];
        }
    }
    size_t cidx = ((size_t)blockIdx.x * 64 + row) * 8 + jj;
    float c0 = c_ws[cidx], c1 = c_ws[cidx + 1];
    float i0 = 1.f / (1.f + expf(-g0[0])), i1 = 1.f / (1.f + expf(-g1[0]));
    float f0 = 1.f / (1.f + expf(-g0[1])), f1 = 1.f / (1.f + expf(-g1[1]));
    float t0 = tanhf(g0[2]),               t1 = tanhf(g1[2]);
    float o0 = 1.f / (1.f + expf(-g0[3])), o1 = 1.f / (1.f + expf(-g1[3]));
    float cn0 = f0 * c0 + i0 * t0;
    float cn1 = f1 * c1 + i1 * t1;
    c_ws[cidx] = cn0; c_ws[cidx + 1] = cn1;
    float h0 = o0 * tanhf(cn0), h1 = o1 * tanhf(cn1);
    unsigned hp = (unsigned)f2b(h0) | ((unsigned)f2b(h1) << 16);
    *(unsigned*)(hout + (size_t)rglob * HH + j0 + jj) = hp;
}

// ---------------- mode-0 fallback (round-1 proven kernels) ----------------
__global__ __launch_bounds__(256) void step_gemm_f32(
    const int* __restrict__ ctx, const int* __restrict__ rsp,
    const float* __restrict__ emb, const float* __restrict__ Wih, const float* __restrict__ Whh,
    const u16* __restrict__ hb, float* __restrict__ gates, int t)
{
    __shared__ __align__(16) u16 As[64][32];
    __shared__ __align__(16) u16 Ws[64][32];
    __shared__ int toks[64];
    const int tid = threadIdx.x;
    const int n0 = blockIdx.x * 64;
    const int r0 = blockIdx.y * 64;
    const int part = blockIdx.z;
    if (tid < 64) {
        int r = r0 + tid;
        toks[tid] = (r < BB) ? ctx[r * TT + t] : rsp[(r - BB) * TT + t];
    }
    __syncthreads();
    const int lane = tid & 63, wave = tid >> 6;
    const int wr = (wave >> 1) * 32, wc = (wave & 1) * 32;
    const int l15 = lane & 15, l4 = lane >> 4;
    f32x4 acc[2][2] = {};
    const int kstart = part * 768;
    const int srow = tid >> 2;
    const int sseg = (tid & 3) * 8;
    for (int it = 0; it < 24; ++it) {
        const int kg = kstart + it * 32;
        const int kk = kg + sseg;
        if (kg < EE) {
            const float* s = emb + (size_t)toks[srow] * EE + kk;
            #pragma unroll
            for (int q = 0; q < 8; ++q) As[srow][sseg + q] = f2b(s[q]);
            const float* sw = Wih + (size_t)(n0 + srow) * EE + kk;
            #pragma unroll
            for (int q = 0; q < 8; ++q) Ws[srow][sseg + q] = f2b(sw[q]);
        } else {
            *(short8*)&As[srow][sseg] = *(const short8*)(hb + (size_t)(r0 + srow) * HH + (kk - EE));
            const float* sw = Whh + (size_t)(n0 + srow) * HH + (kk - EE);
            #pragma unroll
            for (int q = 0; q < 8; ++q) Ws[srow][sseg + q] = f2b(sw[q]);
        }
        __syncthreads();
        #pragma unroll
        for (int mf = 0; mf < 2; ++mf)
            #pragma unroll
            for (int nf = 0; nf < 2; ++nf)
                acc[mf][nf] = mfma16(*(const short8*)&As[wr + mf * 16 + l15][l4 * 8],
                                     *(const short8*)&Ws[wc + nf * 16 + l15][l4 * 8], acc[mf][nf]);
        __syncthreads();
    }
    float* gp = gates + (size_t)part * ROWS * G4;
    #pragma unroll
    for (int mf = 0; mf < 2; ++mf)
        #pragma unroll
        for (int nf = 0; nf < 2; ++nf)
            #pragma unroll
            for (int q = 0; q < 4; ++q) {
                int r = r0 + wr + mf * 16 + l4 * 4 + q;
                int n = n0 + wc + nf * 16 + l15;
                gp[(size_t)r * G4 + n] = acc[mf][nf][q];
            }
}

__global__ __launch_bounds__(256) void lstm_update0(
    const float* __restrict__ gates, const float* __restrict__ bih, const float* __restrict__ bhh,
    u16* __restrict__ hb, float* __restrict__ c)
{
    int idx = blockIdx.x * 256 + threadIdx.x;
    int r = idx >> 8;
    int jj = (idx & 255) * 4;
    const float* gp0 = gates + (size_t)r * G4;
    const float* gp1 = gates + (size_t)(ROWS + r) * G4;
    float gate[4][4];
    #pragma unroll
    for (int g = 0; g < 4; ++g) {
        int n = g * HH + jj;
        f32x4 a = *(const f32x4*)(gp0 + n);
        f32x4 b = *(const f32x4*)(gp1 + n);
        #pragma unroll
        for (int q = 0; q < 4; ++q) gate[g][q] = a[q] + b[q] + bih[n + q] + bhh[n + q];
    }
    int cidx = r * HH + jj;
    f32x4 cv = *(const f32x4*)(c + cidx);
    f32x4 cn; short4v hn;
    #pragma unroll
    for (int q = 0; q < 4; ++q) {
        float si = 1.f / (1.f + expf(-gate[0][q]));
        float sf = 1.f / (1.f + expf(-gate[1][q]));
        float tg = tanhf(gate[2][q]);
        float so = 1.f / (1.f + expf(-gate[3][q]));
        float cval = sf * cv[q] + si * tg;
        cn[q] = cval;
        ((short*)&hn)[q] = (short)f2b(so * tanhf(cval));
    }
    *(f32x4*)(c + cidx) = cn;
    *(short4v*)(hb + cidx) = hn;
}

// ---------------- bilinear head ----------------
__global__ __launch_bounds__(256) void bilinear(
    const u16* __restrict__ hb, const float* __restrict__ M, float* __restrict__ out)
{
    int b = blockIdx.x;
    __shared__ float chs[HH];
    __shared__ float red[256];
    const u16* ch = hb + (size_t)b * HH;
    const u16* rh = hb + (size_t)(BB + b) * HH;
    for (int i = threadIdx.x; i < HH; i += 256) chs[i] = b2f(ch[i]);
    __syncthreads();
    float vj[4] = {0.f, 0.f, 0.f, 0.f};
    for (int i = 0; i < HH; ++i) {
        float chi = chs[i];
        const float* Mr = M + (size_t)i * HH;
        #pragma unroll
        for (int q = 0; q < 4; ++q) vj[q] += chi * Mr[threadIdx.x + q * 256];
    }
    float acc = 0.f;
    #pragma unroll
    for (int q = 0; q < 4; ++q) acc += vj[q] * b2f(rh[threadIdx.x + q * 256]);
    red[threadIdx.x] = acc;
    __syncthreads();
    for (int s = 128; s > 0; s >>= 1) {
        if (threadIdx.x < s) red[threadIdx.x] += red[threadIdx.x + s];
        __syncthreads();
    }
    if (threadIdx.x == 0) out[b] = 1.0f / (1.0f + expf(-red[0]));
}

extern "C" void kernel_launch(void* const* d_in, const int* in_sizes, int n_in,
                              void* d_out, int out_size, void* d_ws, size_t ws_size,
                              hipStream_t stream) {
    const int*   ctx = (const int*)d_in[0];
    const int*   rsp = (const int*)d_in[1];
    const float* emb = (const float*)d_in[2];
    const float* Wih = (const float*)d_in[3];
    const float* Whh = (const float*)d_in[4];
    const float* bih = (const float*)d_in[5];
    const float* bhh = (const float*)d_in[6];
    const float* M   = (const float*)d_in[7];
    float* out = (float*)d_out;

    // workspace layout
    char* w = (char*)d_ws;
    u16*   hbuf  = (u16*)w;   w += (size_t)2 * ROWS * HH * 2;      // 512 KB (double-buffered h)
    float* c_ws  = (float*)w; w += (size_t)ROWS * HH * 4;          // 512 KB
    float* gates = (float*)w; w += (size_t)2 * ROWS * G4 * 4;      // 4 MB (mode 0 only)
    u16*   embb  = (u16*)w;   w += (size_t)32000 * EE * 2;         // 31.25 MB
    u16*   Wihb  = (u16*)w;   w += (size_t)G4 * EE * 2;            // 4 MB
    u16*   Whhb  = (u16*)w;   w += (size_t)G4 * HH * 2;            // 8 MB
    size_t conv_need = (size_t)(w - (char*)d_ws);
    u16*   xg    = (u16*)w;   w += (size_t)TT * ROWS * G4 * 2;     // 160 MB
    size_t xpre_need = (size_t)(w - (char*)d_ws);

    int mode = (ws_size >= xpre_need) ? 2 : (ws_size >= conv_need) ? 1 : 0;

    hipMemsetAsync(hbuf, 0, (size_t)2 * ROWS * HH * 2, stream);
    hipMemsetAsync(c_ws, 0, (size_t)ROWS * HH * 4, stream);

    if (mode >= 1) {
        cvt_kernel<<<16000, 256, 0, stream>>>(emb, embb, 32000 * EE / 4);
        cvt_kernel<<<2048,  256, 0, stream>>>(Wih, Wihb, G4 * EE / 4);
        cvt_kernel<<<4096,  256, 0, stream>>>(Whh, Whhb, G4 * HH / 4);
    }
    if (mode == 2)
        pre_gemm2<<<dim3(G4 / 128, TT), 256, 0, stream>>>(ctx, rsp, embb, Wihb, bih, bhh, xg);

    if (mode >= 1) {
        for (int t = 0; t < TT; ++t) {
            const u16* hin = hbuf + (size_t)(t & 1) * ROWS * HH;
            u16* hout      = hbuf + (size_t)((t + 1) & 1) * ROWS * HH;
            if (mode == 2)
                step_fused<2><<<256, 256, 0, stream>>>(ctx, rsp, embb, Wihb, Whhb, xg,
                                                       bih, bhh, hin, hout, c_ws, t);
            else
                step_fused<1><<<256, 256, 0, stream>>>(ctx, rsp, embb, Wihb, Whhb, xg,
                                                       bih, bhh, hin, hout, c_ws, t);
        }
        bilinear<<<BB, 256, 0, stream>>>(hbuf, M, out);   // final h in buffer 0 (TT even)
    } else {
        // mode 0: round-1 structure, f32 sources converted in staging
        u16* hb = hbuf;           // single buffer
        float* c = c_ws;
        dim3 sg(G4 / 64, ROWS / 64, 2);
        for (int t = 0; t < TT; ++t) {
            step_gemm_f32<<<sg, 256, 0, stream>>>(ctx, rsp, emb, Wih, Whh, hb, gates, t);
            lstm_update0<<<128, 256, 0, stream>>>(gates, bih, bhh, hb, c);
        }
        bilinear<<<BB, 256, 0, stream>>>(hb, M, out);
    }
}